// Round 9
// baseline (68.761 us; speedup 1.0000x reference)
//
#include <hip/hip_runtime.h>
#include <hip/hip_fp16.h>

#define B_ 2
#define C_ 32
#define H_ 256
#define W_ 256
#define K_ 4
#define HW_ (H_ * W_)

typedef float floatx4 __attribute__((ext_vector_type(4)));
typedef unsigned int uintx4 __attribute__((ext_vector_type(4)));

// ---------------------------------------------------------------------------
// Transpose+convert v (B,C,H,W) fp32 -> vt (B,H*W,C) fp16 (64B per pixel).
// Vectorized: 16B nontemporal reads/writes via ext_vector types (the builtin
// rejects HIP_vector_type wrappers).
// ---------------------------------------------------------------------------
__global__ __launch_bounds__(256) void transpose_v_kernel(
    const float* __restrict__ v, unsigned int* __restrict__ vt) {
  __shared__ float tile[32][65];
  int t = threadIdx.x;
  int pix0 = blockIdx.x * 64;          // global pixel index in [0, B*HW)
  int b = pix0 >> 16;
  int pixb = pix0 & (HW_ - 1);
  const float* vb = v + (size_t)b * C_ * HW_;
  int c = t >> 3;
  int f = t & 7;
#pragma unroll
  for (int h = 0; h < 2; ++h) {
    int px = h * 32 + f * 4;
    floatx4 r = __builtin_nontemporal_load(
        (const floatx4*)&vb[(size_t)c * HW_ + pixb + px]);
    tile[c][px + 0] = r.x;
    tile[c][px + 1] = r.y;
    tile[c][px + 2] = r.z;
    tile[c][px + 3] = r.w;
  }
  __syncthreads();
  int px = t >> 2, q = t & 3;
  unsigned int w0, w1, w2, w3;
  { __half2 h2 = __floats2half2_rn(tile[8*q+0][px], tile[8*q+1][px]); __builtin_memcpy(&w0, &h2, 4); }
  { __half2 h2 = __floats2half2_rn(tile[8*q+2][px], tile[8*q+3][px]); __builtin_memcpy(&w1, &h2, 4); }
  { __half2 h2 = __floats2half2_rn(tile[8*q+4][px], tile[8*q+5][px]); __builtin_memcpy(&w2, &h2, 4); }
  { __half2 h2 = __floats2half2_rn(tile[8*q+6][px], tile[8*q+7][px]); __builtin_memcpy(&w3, &h2, 4); }
  uintx4 o;
  o.x = w0; o.y = w1; o.z = w2; o.w = w3;
  __builtin_nontemporal_store(
      o, (uintx4*)((char*)vt + ((size_t)(pix0 + px) << 6) + (q << 4)));
}

// ---------------------------------------------------------------------------
// Main kernel. 256 threads per block; block = 64 consecutive x of one row y.
// XCD-batch partition (confirmed R4): XCDs 0-3 -> batch 0, 4-7 -> batch 1;
// each XCD's gather set (vt[b] = 4 MiB) fits its L2.
// Phase 2 exploits the 3x3 window structure: a 16-lane unit = one (px,k);
// lanes = (dj-tap 0..3 x 16B-quad); one instruction loads a whole window ROW
// whose 3 lines are CONTIGUOUS -> TA coalescer merges into ~2 L2 requests
// (R5-R7 evidence: the wall is L2 random-line throughput, ~7 lines/cy/XCD).
// dj=3 lanes duplicate the dj=2 address (merged, weight 0). Wave = 4 units =
// all k of one px; shfl_xor butterfly over bits 2..5 completes the 36-tap sum.
// ---------------------------------------------------------------------------
__global__ __launch_bounds__(256, 3) void psatt_kernel(
    const float* __restrict__ cost_map, const int* __restrict__ shift_map,
    const unsigned int* __restrict__ vt, float* __restrict__ out) {
  __shared__ float2 lds_ew[64][49];  // [px][slot]; slot = k*12+di*4+dj; pad 49:
                                     // ph2 read conflict-free, ph1 write 4-way
  __shared__ float lds_part[64][4];  // softmax partials per (px,k)
  __shared__ float lds_out[64][33];  // stride 33: conflict-free epilogue

  int t = threadIdx.x;
  int bid = blockIdx.x;            // 0..2047
  int xcd = bid & 7;
  int slot = bid >> 3;             // 0..255
  int b = xcd >> 2;
  int workid = ((xcd & 3) << 8) + slot;  // 0..1023; 64 contiguous rows/XCD
  int y = workid >> 2;
  int x0 = (workid & 3) << 6;

  // ---- phase 1: weights + line byte-offsets -------------------------------
  {
    int k = t >> 6;   // one wave per k-plane
    int px = t & 63;
    int x = x0 + px;
    const float* cm = cost_map + (size_t)(b * K_ + k) * HW_;
    const int* s0 = shift_map + (size_t)((b * 2 + 0) * K_ + k) * HW_;
    const int* s1 = shift_map + (size_t)((b * 2 + 1) * K_ + k) * HW_;
    float psum = 0.f;
#pragma unroll
    for (int di = 0; di < 3; ++di) {
      int ny = y + di - 1;
      bool yin = (unsigned)ny < (unsigned)H_;
#pragma unroll
      for (int dj = 0; dj < 3; ++dj) {
        int nx = x + dj - 1;
        bool inb = yin && ((unsigned)nx < (unsigned)W_);
        int nidx = ny * W_ + nx;
        float cost;
        int si, sj;
        if (inb) {
          cost = cm[nidx];
          si = s0[nidx] + (1 - di);
          sj = s1[nidx] + (1 - dj);
        } else {
          cost = 10.0f;     // pad value of cost_map
          si = 11 - di;     // pad value 10 + (1 - di)
          sj = 11 - dj;
        }
        float e = __expf(-cost);  // T = 1; no max-sub needed (range safe)
        int ii = min(max(si, 0), H_ - 1);
        int jj = min(max(sj, 0), W_ - 1);
        float offf = __int_as_float((ii * W_ + jj) << 6);  // 64B line base
        lds_ew[px][k * 12 + di * 4 + dj] = make_float2(e, offf);
        if (dj == 2) {  // idle-lane slot: zero weight, duplicate address
          lds_ew[px][k * 12 + di * 4 + 3] = make_float2(0.f, offf);
        }
        psum += e;
      }
    }
    lds_part[px][k] = psum;
  }
  __syncthreads();  // single barrier: lds_ew + lds_part ready

  // ---- phase 2: row-window gathers + butterfly reduce ---------------------
  {
    int lane = t & 63;
    int wv = t >> 6;              // wave id: 16 px each
    int u = lane >> 4;            // unit = k
    int dj = (lane >> 2) & 3;     // tap within row (3 real + 1 dup)
    int q = lane & 3;             // 16B quad: channels 8q..8q+7
    const char* base = (const char*)vt + ((size_t)b * HW_ << 6);  // SGPR base
    unsigned int qoff = (unsigned int)(q << 4);
    int sbase = u * 12 + dj;
    int jsel = lane >> 2;         // 0..15; valid < 8
#pragma unroll 1
    for (int batch = 0; batch < 4; ++batch) {
      int pxb = (wv << 4) + (batch << 2);
      uint4 hv[4][3];
      float ew[4][3];
#pragma unroll
      for (int pp = 0; pp < 4; ++pp) {
#pragma unroll
        for (int di = 0; di < 3; ++di) {
          float2 eo = lds_ew[pxb + pp][sbase + di * 4];  // conflict-free b64
          ew[pp][di] = eo.x;
          unsigned int voff = (unsigned int)__float_as_int(eo.y) + qoff;
          hv[pp][di] = *(const uint4*)(base + voff);  // adjacent lanes =
        }                                             // adjacent lines: merge
      }
#pragma unroll
      for (int pp = 0; pp < 4; ++pp) {
        int px = pxb + pp;
        float acc[8] = {0.f, 0.f, 0.f, 0.f, 0.f, 0.f, 0.f, 0.f};
#pragma unroll
        for (int di = 0; di < 3; ++di) {
          float e = ew[pp][di];
          uint4 hvv = hv[pp][di];
          __half2 h0, h1, h2, h3;
          __builtin_memcpy(&h0, &hvv.x, 4);
          __builtin_memcpy(&h1, &hvv.y, 4);
          __builtin_memcpy(&h2, &hvv.z, 4);
          __builtin_memcpy(&h3, &hvv.w, 4);
          float2 f0 = __half22float2(h0);
          float2 f1 = __half22float2(h1);
          float2 f2 = __half22float2(h2);
          float2 f3 = __half22float2(h3);
          acc[0] += e * f0.x; acc[1] += e * f0.y;
          acc[2] += e * f1.x; acc[3] += e * f1.y;
          acc[4] += e * f2.x; acc[5] += e * f2.y;
          acc[6] += e * f3.x; acc[7] += e * f3.y;
        }
        // butterfly over bits 2..5 (dj x k): completes 36-tap sum per q-class
#pragma unroll
        for (int j = 0; j < 8; ++j) {
          acc[j] += __shfl_xor(acc[j], 4);
          acc[j] += __shfl_xor(acc[j], 8);
          acc[j] += __shfl_xor(acc[j], 16);
          acc[j] += __shfl_xor(acc[j], 32);
        }
        float4 ps = *(const float4*)&lds_part[px][0];  // broadcast
        float inv = 1.0f / (ps.x + ps.y + ps.z + ps.w);
        float val = acc[0];
#pragma unroll
        for (int j = 1; j < 8; ++j) val = (jsel == j) ? acc[j] : val;
        if (lane < 32) lds_out[px][(q << 3) + jsel] = val * inv;
      }
    }
  }
  __syncthreads();

  // ---- epilogue: transpose to channel-major, nontemporal coalesced stores -
  {
    int px = t & 63;
#pragma unroll
    for (int it = 0; it < 8; ++it) {
      int c = (t >> 6) + it * 4;
      __builtin_nontemporal_store(
          lds_out[px][c],
          &out[((size_t)(b * C_ + c) * H_ + y) * W_ + x0 + px]);
    }
  }
}

extern "C" void kernel_launch(void* const* d_in, const int* in_sizes, int n_in,
                              void* d_out, int out_size, void* d_ws, size_t ws_size,
                              hipStream_t stream) {
  const float* v = (const float*)d_in[0];
  const float* cost_map = (const float*)d_in[1];
  const int* shift_map = (const int*)d_in[2];
  float* out = (float*)d_out;

  unsigned int* vt = (unsigned int*)d_ws;  // B*HW*16 uints = 8.4 MB
  const int grid = B_ * H_ * (W_ / 64);    // 2048 blocks

  transpose_v_kernel<<<B_ * HW_ / 64, 256, 0, stream>>>(v, vt);
  psatt_kernel<<<grid, 256, 0, stream>>>(cost_map, shift_map, vt, out);
}

// Round 10
// 44.461 us; speedup vs baseline: 1.5465x; 1.5465x over previous
//
#include <hip/hip_runtime.h>
#include <hip/hip_fp16.h>

#define B_ 2
#define C_ 32
#define H_ 256
#define W_ 256
#define K_ 4
#define HW_ (H_ * W_)

typedef float floatx4 __attribute__((ext_vector_type(4)));
typedef unsigned int uintx4 __attribute__((ext_vector_type(4)));

// ---------------------------------------------------------------------------
// Transpose+convert v (B,C,H,W) fp32 -> vt (B,H*W,C) fp16 (64B per pixel).
// ---------------------------------------------------------------------------
__global__ __launch_bounds__(256) void transpose_v_kernel(
    const float* __restrict__ v, unsigned int* __restrict__ vt) {
  __shared__ float tile[32][65];
  int t = threadIdx.x;
  int pix0 = blockIdx.x * 64;          // global pixel index in [0, B*HW)
  int b = pix0 >> 16;
  int pixb = pix0 & (HW_ - 1);
  const float* vb = v + (size_t)b * C_ * HW_;
  int c = t >> 3;
  int f = t & 7;
#pragma unroll
  for (int h = 0; h < 2; ++h) {
    int px = h * 32 + f * 4;
    floatx4 r = __builtin_nontemporal_load(
        (const floatx4*)&vb[(size_t)c * HW_ + pixb + px]);
    tile[c][px + 0] = r.x;
    tile[c][px + 1] = r.y;
    tile[c][px + 2] = r.z;
    tile[c][px + 3] = r.w;
  }
  __syncthreads();
  int px = t >> 2, q = t & 3;
  unsigned int w0, w1, w2, w3;
  { __half2 h2 = __floats2half2_rn(tile[8*q+0][px], tile[8*q+1][px]); __builtin_memcpy(&w0, &h2, 4); }
  { __half2 h2 = __floats2half2_rn(tile[8*q+2][px], tile[8*q+3][px]); __builtin_memcpy(&w1, &h2, 4); }
  { __half2 h2 = __floats2half2_rn(tile[8*q+4][px], tile[8*q+5][px]); __builtin_memcpy(&w2, &h2, 4); }
  { __half2 h2 = __floats2half2_rn(tile[8*q+6][px], tile[8*q+7][px]); __builtin_memcpy(&w3, &h2, 4); }
  uintx4 o;
  o.x = w0; o.y = w1; o.z = w2; o.w = w3;
  __builtin_nontemporal_store(
      o, (uintx4*)((char*)vt + ((size_t)(pix0 + px) << 6) + (q << 4)));
}

// ---------------------------------------------------------------------------
// Main kernel: ONE WAVE per block, 16 pixels of one row; 8192 blocks.
// R10 rationale: R6's dataflow (SADDR dwordx4 gathers) was latency-bound at
// ~3 waves/SIMD (compiler refuses deep ILP batches: VGPR_Count=52 despite
// 18-deep source batches). One-wave blocks + small LDS (8.5KB) + VGPR~52
// -> ~6-8 waves/SIMD resident: concurrency from TLP instead of ILP, and
// __syncthreads degenerates to intra-wave ordering (no convoys).
// XCD-batch partition kept (confirmed R4: FETCH 100->25MB): XCDs 0-3 own
// batch 0, XCDs 4-7 batch 1; each XCD's gather set (4 MiB) fits its L2.
// ---------------------------------------------------------------------------
__global__ __launch_bounds__(64, 6) void psatt_kernel(
    const float* __restrict__ cost_map, const int* __restrict__ shift_map,
    const unsigned int* __restrict__ vt, float* __restrict__ out) {
  __shared__ float2 lds_ew[16][37];  // (e, byte-off); [px][m] conflict-free
  __shared__ float lds_part[16][4];  // softmax partials per (px,k)
  __shared__ float lds_out[16][33];  // conflict-free epilogue transpose

  int t = threadIdx.x;
  // XCD-aware decomposition (empirical round-robin: XCD = blockIdx % 8).
  int bid = blockIdx.x;            // 0..8191
  int xcd = bid & 7;
  int slot = bid >> 3;             // 0..1023
  int b = xcd >> 2;                // XCDs 0-3 -> batch 0, 4-7 -> batch 1
  int workid = ((xcd & 3) << 10) + slot;  // 0..4095; 64 contiguous rows/XCD
  int y = workid >> 4;             // W/16 = 16 tiles per row
  int x0 = (workid & 15) << 4;

  // ---- phase 1: weights + line byte-offsets -------------------------------
  {
    int k = t >> 4;   // 4 k-groups of 16 lanes
    int px = t & 15;
    int x = x0 + px;
    const float* cm = cost_map + (size_t)(b * K_ + k) * HW_;
    const int* s0 = shift_map + (size_t)((b * 2 + 0) * K_ + k) * HW_;
    const int* s1 = shift_map + (size_t)((b * 2 + 1) * K_ + k) * HW_;
    float psum = 0.f;
#pragma unroll
    for (int di = 0; di < 3; ++di) {
      int ny = y + di - 1;
      bool yin = (unsigned)ny < (unsigned)H_;
#pragma unroll
      for (int dj = 0; dj < 3; ++dj) {
        int nx = x + dj - 1;
        bool inb = yin && ((unsigned)nx < (unsigned)W_);
        int nidx = ny * W_ + nx;
        float cost;
        int si, sj;
        if (inb) {
          cost = cm[nidx];
          si = s0[nidx] + (1 - di);
          sj = s1[nidx] + (1 - dj);
        } else {
          cost = 10.0f;     // pad value of cost_map
          si = 11 - di;     // pad value 10 + (1 - di)
          sj = 11 - dj;
        }
        float e = __expf(-cost);  // T = 1; no max-sub needed (range safe)
        int ii = min(max(si, 0), H_ - 1);
        int jj = min(max(sj, 0), W_ - 1);
        int m = k * 9 + di * 3 + dj;
        lds_ew[px][m] = make_float2(e, __int_as_float((ii * W_ + jj) << 6));
        psum += e;
      }
    }
    lds_part[px][k] = psum;
  }
  __syncthreads();  // intra-wave: just an LDS visibility fence

  // ---- phase 2: gather-sum; SADDR dwordx4; two 18-tap batches -------------
  {
    int q = t & 3;      // 16B quad within pixel: channels 8q..8q+7
    int px = t >> 2;    // 0..15
    const char* base = (const char*)vt + ((size_t)b * HW_ << 6);  // SGPR base
    unsigned int qoff = (unsigned int)(q << 4);
    float acc[8] = {0.f, 0.f, 0.f, 0.f, 0.f, 0.f, 0.f, 0.f};
#pragma unroll
    for (int half = 0; half < 2; ++half) {
      uint4 hv[18];
      float ew[18];
#pragma unroll
      for (int m = 0; m < 18; ++m) {
        float2 eo = lds_ew[px][half * 18 + m];     // one ds_read_b64
        ew[m] = eo.x;
        unsigned int voff = (unsigned int)__float_as_int(eo.y) + qoff;
        hv[m] = *(const uint4*)(base + voff);      // global_load_dwordx4 saddr
      }
#pragma unroll
      for (int m = 0; m < 18; ++m) {
        float e = ew[m];
        __half2 h0, h1, h2, h3;
        __builtin_memcpy(&h0, &hv[m].x, 4);
        __builtin_memcpy(&h1, &hv[m].y, 4);
        __builtin_memcpy(&h2, &hv[m].z, 4);
        __builtin_memcpy(&h3, &hv[m].w, 4);
        float2 f0 = __half22float2(h0);
        float2 f1 = __half22float2(h1);
        float2 f2 = __half22float2(h2);
        float2 f3 = __half22float2(h3);
        acc[0] += e * f0.x; acc[1] += e * f0.y;
        acc[2] += e * f1.x; acc[3] += e * f1.y;
        acc[4] += e * f2.x; acc[5] += e * f2.y;
        acc[6] += e * f3.x; acc[7] += e * f3.y;
      }
    }
    float4 ps = *(const float4*)&lds_part[px][0];  // broadcast
    float inv = 1.0f / (ps.x + ps.y + ps.z + ps.w);
#pragma unroll
    for (int j = 0; j < 8; ++j) {
      lds_out[px][8 * q + j] = acc[j] * inv;
    }
  }
  __syncthreads();

  // ---- epilogue: transpose to channel-major, nontemporal coalesced stores -
  {
    int px = t & 15;
#pragma unroll
    for (int it = 0; it < 8; ++it) {
      int c = (t >> 4) + it * 4;
      __builtin_nontemporal_store(
          lds_out[px][c],
          &out[((size_t)(b * C_ + c) * H_ + y) * W_ + x0 + px]);
    }
  }
}

extern "C" void kernel_launch(void* const* d_in, const int* in_sizes, int n_in,
                              void* d_out, int out_size, void* d_ws, size_t ws_size,
                              hipStream_t stream) {
  const float* v = (const float*)d_in[0];
  const float* cost_map = (const float*)d_in[1];
  const int* shift_map = (const int*)d_in[2];
  float* out = (float*)d_out;

  unsigned int* vt = (unsigned int*)d_ws;  // B*HW*16 uints = 8.4 MB
  const int grid = B_ * H_ * (W_ / 16);    // 8192 one-wave blocks

  transpose_v_kernel<<<B_ * HW_ / 64, 256, 0, stream>>>(v, vt);
  psatt_kernel<<<grid, 64, 0, stream>>>(cost_map, shift_map, vt, out);
}